// Round 4
// baseline (442.071 us; speedup 1.0000x reference)
//
#include <hip/hip_runtime.h>
#include <hip/hip_fp16.h>

typedef unsigned short u16;
typedef __attribute__((ext_vector_type(8))) short bf16x8;
typedef __attribute__((ext_vector_type(4))) float floatx4;
typedef __attribute__((ext_vector_type(2))) _Float16 half2v;

#define NPIX 625
#define NCAPS 20000
#define K2 9216

__device__ __forceinline__ u16 f2bf(float f) {
  unsigned u = __float_as_uint(f);
  return (u16)((u + 0x7fffu + ((u >> 16) & 1u)) >> 16);
}

__device__ __forceinline__ unsigned h16(float f) {
  union { _Float16 h; u16 b; } c;
  c.h = (_Float16)f;
  return (unsigned)c.b;
}

__device__ __forceinline__ half2v as_h2(unsigned u) {
  union { unsigned i; half2v h; } c;
  c.i = u;
  return c.h;
}

__device__ __forceinline__ float dot2f(unsigned a, unsigned b, float c) {
#if __has_builtin(__builtin_amdgcn_fdot2)
  return __builtin_amdgcn_fdot2(as_h2(a), as_h2(b), c, false);
#else
  half2v x = as_h2(a), y = as_h2(b);
  return fmaf((float)x[1], (float)y[1], fmaf((float)x[0], (float)y[0], c));
#endif
}

__device__ __forceinline__ float dotrow16(uint4 w, uint4 u) {
  float s = dot2f(w.x, u.x, 0.f);
  s = dot2f(w.y, u.y, s);
  s = dot2f(w.z, u.z, s);
  s = dot2f(w.w, u.w, s);
  return s;
}

__device__ __forceinline__ float dot8v(float4 a0, float4 a1, float4 b0, float4 b1) {
  float s = a0.x * b0.x;
  s = fmaf(a0.y, b0.y, s); s = fmaf(a0.z, b0.z, s); s = fmaf(a0.w, b0.w, s);
  s = fmaf(a1.x, b1.x, s); s = fmaf(a1.y, b1.y, s);
  s = fmaf(a1.z, b1.z, s); s = fmaf(a1.w, b1.w, s);
  return s;
}

#define GLDS16(g, l) __builtin_amdgcn_global_load_lds( \
    (const __attribute__((address_space(1))) void*)(g), \
    (__attribute__((address_space(3))) void*)(l), 16, 0, 0)

#define MFMA16(a, b, c) __builtin_amdgcn_mfma_f32_16x16x32_bf16((a), (b), (c), 0, 0, 0)

// ---------- merged: w2/w3 prep (blocks 0..383) + conv1 (blocks 384..1183) ----------
// w2 pack: A2n[(kt*256 + oc)*2304 + tl*256 + c], tap g = kt*9 + tl.
__global__ void prep_conv1(const float* __restrict__ w2, const float* __restrict__ w3,
                           u16* __restrict__ A2c, u16* __restrict__ A3,
                           const float* __restrict__ x, const float* __restrict__ w1,
                           const float* __restrict__ b1, u16* __restrict__ x1p) {
  if (blockIdx.x < 256) {
    const int oc = blockIdx.x, c = threadIdx.x;
    const float* src = w2 + (oc * 256 + c) * 36;
    float v[36];
#pragma unroll
    for (int k = 0; k < 9; k++) {
      const float4 q = *(const float4*)(src + k * 4);
      v[k * 4 + 0] = q.x; v[k * 4 + 1] = q.y; v[k * 4 + 2] = q.z; v[k * 4 + 3] = q.w;
    }
#pragma unroll
    for (int g = 0; g < 36; g++) {
      const int ktp = g / 9, tl = g % 9;
      A2c[(ktp * 256 + oc) * 2304 + tl * 256 + c] = f2bf(v[g]);
    }
  } else if (blockIdx.x < 384) {
    const int j = (blockIdx.x - 256) * 1024 + threadIdx.x * 4;
    const float4 q = *(const float4*)(w3 + j);
    ushort4 p;
    p.x = f2bf(q.x); p.y = f2bf(q.y); p.z = f2bf(q.z); p.w = f2bf(q.w);
    *(ushort4*)(A3 + j) = p;
  } else {
    const int blk = blockIdx.x - 384;     // 800 = 32 b * 25 rows
    const int b = blk / 25, i = blk % 25;
    const int f = threadIdx.x;
    float wreg[36];
#pragma unroll
    for (int k = 0; k < 36; k++) wreg[k] = w1[f * 36 + k];
    float bias = b1[f];
    const float* xb = x + b * 54 * 54 + (2 * i) * 54;
    for (int j = 0; j < 25; j++) {
      float acc = bias;
#pragma unroll
      for (int ki = 0; ki < 6; ki++)
#pragma unroll
        for (int kj = 0; kj < 6; kj++)
          acc = fmaf(xb[ki * 54 + 2 * j + kj], wreg[ki * 6 + kj], acc);
      x1p[(((b * 30 + i + 2) * 30) + (j + 2)) * 256 + f] = f2bf(fmaxf(acc, 0.f));
    }
  }
}

// ---------- conv2 implicit GEMM, BM=256 x BN=320, BK=64, split-K=4 ----------
// 8 waves (2m x 4n), wave tile 128x80 (8x5 frags). 2-buffer LDS (147 KB), grid
// 252 blocks = one dispatch round. XCD-aware swizzle (T1): bid%8 = XCD heuristic;
// XCD x works kt = x&3 and a contiguous ntile half -> each XCD's L2 holds exactly
// ONE 1.18 MB A-slice + halo-sharing contiguous B windows (round-3 PMC showed
// 195 MB L2-miss traffic from 4 slices + scattered windows thrashing 4 MB L2).
// All 9 staging loads for tile t+1 issue in P1 (~3.5 phases issue->drain slack).
__global__ __launch_bounds__(512, 1) void conv2_gemm(const u16* __restrict__ A2n,
    const u16* __restrict__ x1p, u16* __restrict__ P) {
  // per buffer: A = 256x64 u16 (0..16383), B = 320x64 u16 (16384..36863)
  __shared__ __align__(16) u16 lds[2][36864];
  const int tid = threadIdx.x;
  const int lane = tid & 63, wave = tid >> 6;
  // --- XCD swizzle: bijective (kt, ntile) <- bid; perf heuristic only ---
  const int bid = blockIdx.x;                    // 0..251
  const int xcd = bid & 7, idx = bid >> 3;       // idx 0..31 (x<4), 0..30 (x>=4)
  const int kt = xcd & 3;
  const int ntile = (xcd >> 2) ? (32 + idx) : idx; // halves: 0..31 | 32..62
  const int wm = wave & 1, wn = wave >> 1;       // wm: oc 128-half, wn: n 80-block
  const int lrow = lane & 15, kg = lane >> 4;

  const int trow = tid >> 3;                     // staging row within a 64-row group
  const int xoff = 8 * ((tid & 7) ^ (trow & 7)); // inverse-swizzle on global source
  const u16* aSrc = A2n + (kt * 256 + trow) * 2304 + xoff;
  const int nb = ntile * 320;                    // 63*320 = 20160, clamp at 20000
  auto pixrow = [&](int r) {
    int n = nb + r;
    if (n > NCAPS - 1) n = NCAPS - 1;
    const int b = n / NPIX, p = n % NPIX;
    const int i = p / 25, j = p % 25;
    return ((b * 30 + i) * 30 + j) * 256;
  };
  const u16* bSrc0 = x1p + pixrow(trow) + xoff;
  const u16* bSrc1 = x1p + pixrow(64 + trow) + xoff;
  const u16* bSrc2 = x1p + pixrow(128 + trow) + xoff;
  const u16* bSrc3 = x1p + pixrow(192 + trow) + xoff;
  const u16* bSrc4 = x1p + pixrow(256 + trow) + xoff;

  auto stageA = [&](u16* L, int tt) {            // 4 loads: A rows 0..255, k-step tt
    const u16* a = aSrc + tt * 64;
    GLDS16(a,               L + tid * 8);
    GLDS16(a + 64 * 2304,   L + 4096 + tid * 8);
    GLDS16(a + 128 * 2304,  L + 8192 + tid * 8);
    GLDS16(a + 192 * 2304,  L + 12288 + tid * 8);
  };
  auto stageB = [&](u16* L, int tt) {            // 5 loads: B rows 0..319
    const int g = kt * 9 + (tt >> 2);
    const int boff = ((g / 6) * 30 + (g % 6)) * 256 + (tt & 3) * 64;
    GLDS16(bSrc0 + boff, L + 16384 + tid * 8);
    GLDS16(bSrc1 + boff, L + 20480 + tid * 8);
    GLDS16(bSrc2 + boff, L + 24576 + tid * 8);
    GLDS16(bSrc3 + boff, L + 28672 + tid * 8);
    GLDS16(bSrc4 + boff, L + 32768 + tid * 8);
  };

  floatx4 acc[8][5] = {};
  const int jx0 = 8 * (kg ^ (lrow & 7));         // swizzled 16B-slot, k-half 0
  const int jx1 = 8 * ((4 + kg) ^ (lrow & 7));   // k-half 1
  const int arow = wm * 128 + lrow;
  const int brow = wn * 80 + lrow;

  // ---- prologue: stage tile 0, full drain once ----
  stageA(lds[0], 0);
  stageB(lds[0], 0);
  asm volatile("s_waitcnt vmcnt(0)" ::: "memory");
  __builtin_amdgcn_s_barrier();

  for (int t = 0; t < 36; t++) {
    u16* Cur = lds[t & 1];
    u16* Oth = lds[(t & 1) ^ 1];
    const bool st = (t < 35);
    bf16x8 af[4], bv[5];

    // ---- P1: read A kh0 lo + B kh0; stage ALL of tile t+1; barrier; MFMA ----
#pragma unroll
    for (int fm = 0; fm < 4; fm++)
      af[fm] = *(const bf16x8*)(Cur + (arow + fm * 16) * 64 + jx0);
#pragma unroll
    for (int fn = 0; fn < 5; fn++)
      bv[fn] = *(const bf16x8*)(Cur + 16384 + (brow + fn * 16) * 64 + jx0);
    if (st) { stageA(Oth, t + 1); stageB(Oth, t + 1); }
    asm volatile("" ::: "memory");
    __builtin_amdgcn_s_barrier();
    __builtin_amdgcn_s_setprio(1);
#pragma unroll
    for (int fm = 0; fm < 4; fm++)
#pragma unroll
      for (int fn = 0; fn < 5; fn++)
        acc[fm][fn] = MFMA16(af[fm], bv[fn], acc[fm][fn]);
    __builtin_amdgcn_s_setprio(0);
    __builtin_amdgcn_sched_barrier(0);
    __builtin_amdgcn_s_barrier();

    // ---- P2: read A kh0 hi; barrier; MFMA ----
    bf16x8 ag[4];
#pragma unroll
    for (int fm = 0; fm < 4; fm++)
      ag[fm] = *(const bf16x8*)(Cur + (arow + 64 + fm * 16) * 64 + jx0);
    asm volatile("" ::: "memory");
    __builtin_amdgcn_s_barrier();
    __builtin_amdgcn_s_setprio(1);
#pragma unroll
    for (int fm = 0; fm < 4; fm++)
#pragma unroll
      for (int fn = 0; fn < 5; fn++)
        acc[4 + fm][fn] = MFMA16(ag[fm], bv[fn], acc[4 + fm][fn]);
    __builtin_amdgcn_s_setprio(0);
    __builtin_amdgcn_sched_barrier(0);
    __builtin_amdgcn_s_barrier();

    // ---- P3: read A kh1 lo + B kh1; barrier; MFMA ----
#pragma unroll
    for (int fm = 0; fm < 4; fm++)
      af[fm] = *(const bf16x8*)(Cur + (arow + fm * 16) * 64 + jx1);
#pragma unroll
    for (int fn = 0; fn < 5; fn++)
      bv[fn] = *(const bf16x8*)(Cur + 16384 + (brow + fn * 16) * 64 + jx1);
    asm volatile("" ::: "memory");
    __builtin_amdgcn_s_barrier();
    __builtin_amdgcn_s_setprio(1);
#pragma unroll
    for (int fm = 0; fm < 4; fm++)
#pragma unroll
      for (int fn = 0; fn < 5; fn++)
        acc[fm][fn] = MFMA16(af[fm], bv[fn], acc[fm][fn]);
    __builtin_amdgcn_s_setprio(0);
    __builtin_amdgcn_sched_barrier(0);
    __builtin_amdgcn_s_barrier();

    // ---- P4: read A kh1 hi; barrier; MFMA; vmcnt drain; barrier (validates t+1) ----
#pragma unroll
    for (int fm = 0; fm < 4; fm++)
      ag[fm] = *(const bf16x8*)(Cur + (arow + 64 + fm * 16) * 64 + jx1);
    asm volatile("" ::: "memory");
    __builtin_amdgcn_s_barrier();
    __builtin_amdgcn_s_setprio(1);
#pragma unroll
    for (int fm = 0; fm < 4; fm++)
#pragma unroll
      for (int fn = 0; fn < 5; fn++)
        acc[4 + fm][fn] = MFMA16(ag[fm], bv[fn], acc[4 + fm][fn]);
    __builtin_amdgcn_s_setprio(0);
    __builtin_amdgcn_sched_barrier(0);
    asm volatile("s_waitcnt vmcnt(0)" ::: "memory");
    __builtin_amdgcn_sched_barrier(0);
    __builtin_amdgcn_s_barrier();
  }

  u16* Pk = P + kt * 5120000;
#pragma unroll
  for (int fn = 0; fn < 5; fn++) {
    const int n = nb + wn * 80 + fn * 16 + lrow;
    if (n < NCAPS) {
#pragma unroll
      for (int fm = 0; fm < 8; fm++) {
        const int oc = wm * 128 + fm * 16 + kg * 4;
        ushort4 pk;
        pk.x = f2bf(acc[fm][fn][0]);
        pk.y = f2bf(acc[fm][fn][1]);
        pk.z = f2bf(acc[fm][fn][2]);
        pk.w = f2bf(acc[fm][fn][3]);
        *(ushort4*)(Pk + n * 256 + oc) = pk;
      }
    }
  }
}

// ---------- conv2 split-K reduce: y = bf16(relu(sum P[0..3] + bias)) ----------
__global__ void conv2_red(const u16* __restrict__ P, const float* __restrict__ bias2,
                          u16* __restrict__ y) {
  const int idx = blockIdx.x * 256 + threadIdx.x;
  const ushort4 p0 = *(const ushort4*)(P + idx * 4);
  const ushort4 p1 = *(const ushort4*)(P + 5120000 + idx * 4);
  const ushort4 p2 = *(const ushort4*)(P + 10240000 + idx * 4);
  const ushort4 p3 = *(const ushort4*)(P + 15360000 + idx * 4);
  const float4 bs = *(const float4*)(bias2 + ((idx * 4) & 255));
  auto bf = [](unsigned v) { return __uint_as_float(v << 16); };
  float sx = bf(p0.x) + bf(p1.x) + bf(p2.x) + bf(p3.x) + bs.x;
  float sy = bf(p0.y) + bf(p1.y) + bf(p2.y) + bf(p3.y) + bs.y;
  float sz = bf(p0.z) + bf(p1.z) + bf(p2.z) + bf(p3.z) + bs.z;
  float sw = bf(p0.w) + bf(p1.w) + bf(p2.w) + bf(p3.w) + bs.w;
  ushort4 pk;
  pk.x = f2bf(fmaxf(sx, 0.f));
  pk.y = f2bf(fmaxf(sy, 0.f));
  pk.z = f2bf(fmaxf(sz, 0.f));
  pk.w = f2bf(fmaxf(sw, 0.f));
  *(ushort4*)(y + idx * 4) = pk;
}

// ---------- conv3 1x1 GEMM, split-K=2 (kt0: x1 half, kt1: y half) ----------
__global__ __launch_bounds__(256) void conv3_gemm(const u16* __restrict__ A3,
    const u16* __restrict__ x1p, const u16* __restrict__ y, u16* __restrict__ P3) {
  __shared__ u16 As[128 * 32];
  __shared__ u16 Bs[128 * 32];
  const int tid = threadIdx.x;
  const int lane = tid & 63, wave = tid >> 6;
  const int mtile = blockIdx.x, ntile = blockIdx.y, kt = blockIdx.z;

  const int seg0 = tid, seg1 = tid + 256;
  const u16* ga0 = A3 + (mtile * 128 + (seg0 >> 2)) * 512 + (seg0 & 3) * 8 + kt * 256;
  const u16* ga1 = A3 + (mtile * 128 + (seg1 >> 2)) * 512 + (seg1 & 3) * 8 + kt * 256;

  auto mkbase = [&](int seg) {
    int n = ntile * 128 + (seg >> 2);
    if (n > NCAPS - 1) n = NCAPS - 1;
    if (kt == 0) {
      int b = n / NPIX, p = n % NPIX;
      int i = p / 25, j = p % 25;
      return x1p + ((b * 30 + i + 2) * 30 + (j + 2)) * 256 + (seg & 3) * 8;
    }
    return y + n * 256 + (seg & 3) * 8;
  };
  const u16* gs0 = mkbase(seg0);
  const u16* gs1 = mkbase(seg1);

  floatx4 acc[4][4] = {};
  const int wm = wave & 1, wn = wave >> 1;
  const int lrow = lane & 15, kgrp = lane >> 4;

  for (int kc = 0; kc < 8; kc++) {
    GLDS16(ga0 + kc * 32, As + seg0 * 8);
    GLDS16(ga1 + kc * 32, As + seg1 * 8);
    GLDS16(gs0 + kc * 32, Bs + seg0 * 8);
    GLDS16(gs1 + kc * 32, Bs + seg1 * 8);
    __syncthreads();
    bf16x8 af[4], bfr[4];
#pragma unroll
    for (int tt = 0; tt < 4; tt++) {
      af[tt]  = *(const bf16x8*)(As + (wm * 64 + tt * 16 + lrow) * 32 + kgrp * 8);
      bfr[tt] = *(const bf16x8*)(Bs + (wn * 64 + tt * 16 + lrow) * 32 + kgrp * 8);
    }
#pragma unroll
    for (int tm = 0; tm < 4; tm++)
#pragma unroll
      for (int tn = 0; tn < 4; tn++)
        acc[tm][tn] = __builtin_amdgcn_mfma_f32_16x16x32_bf16(af[tm], bfr[tn], acc[tm][tn], 0, 0, 0);
    __syncthreads();
  }

  u16* Pk = P3 + kt * 5120000;
  const int nb = ntile * 128 + wn * 64;
  const int fb = mtile * 128 + wm * 64 + kgrp * 4;
#pragma unroll
  for (int tn = 0; tn < 4; tn++) {
    int n = nb + tn * 16 + lrow;
    if (n < NCAPS) {
#pragma unroll
      for (int tm = 0; tm < 4; tm++) {
        int f0 = fb + tm * 16;
        ushort4 pk;
        pk.x = f2bf(acc[tm][tn][0]);
        pk.y = f2bf(acc[tm][tn][1]);
        pk.z = f2bf(acc[tm][tn][2]);
        pk.w = f2bf(acc[tm][tn][3]);
        *(ushort4*)(Pk + n * 256 + f0) = pk;
      }
    }
  }
}

// ---------- merged: W->f16 swizzle (blocks 0..9999) + u (blocks 10000..12499) ----------
__global__ void prep_caps(const float* __restrict__ W, u16* __restrict__ Wbs,
                          const u16* __restrict__ P3, const float* __restrict__ b3,
                          const float* __restrict__ pcw, const float* __restrict__ pcb,
                          unsigned* __restrict__ u2) {
  const int tid = threadIdx.x;
  if (blockIdx.x < 10000) {
    int r = blockIdx.x * 256 + tid;
    int n = r >> 7, eo = r & 127;
    int e = eo >> 4, o = eo & 15;
    const float* src = W + n * 1024 + eo * 8;
    const float4 v0 = *(const float4*)src;
    const float4 v1 = *(const float4*)(src + 4);
    u16* dst = Wbs + n * 1088 + e * 136 + o * 8;
    ushort4 p0, p1;
    p0.x = (u16)h16(v0.x); p0.y = (u16)h16(v0.y); p0.z = (u16)h16(v0.z); p0.w = (u16)h16(v0.w);
    p1.x = (u16)h16(v1.x); p1.y = (u16)h16(v1.y); p1.z = (u16)h16(v1.z); p1.w = (u16)h16(v1.w);
    *(ushort4*)dst = p0;
    *(ushort4*)(dst + 4) = p1;
  } else {
    const int blk = blockIdx.x - 10000;
    const int b = tid >> 3, o = tid & 7;
    for (int k = 0; k < 8; k++) {
      const int n = blk * 8 + k;
      const int g = n / NPIX, p = n % NPIX;
      const u16* pa = P3 + ((b * NPIX + p) * 256 + g * 8);
      const uint4 qa = *(const uint4*)pa;
      const uint4 qb = *(const uint4*)(pa + 5120000);
      const float* bp = b3 + g * 8;
      const float4 bb0 = *(const float4*)bp;
      const float4 bb1 = *(const float4*)(bp + 4);
      float4 c0, c1;
      c0.x = __uint_as_float(qa.x << 16) + __uint_as_float(qb.x << 16) + bb0.x;
      c0.y = __uint_as_float(qa.x & 0xffff0000u) + __uint_as_float(qb.x & 0xffff0000u) + bb0.y;
      c0.z = __uint_as_float(qa.y << 16) + __uint_as_float(qb.y << 16) + bb0.z;
      c0.w = __uint_as_float(qa.y & 0xffff0000u) + __uint_as_float(qb.y & 0xffff0000u) + bb0.w;
      c1.x = __uint_as_float(qa.z << 16) + __uint_as_float(qb.z << 16) + bb1.x;
      c1.y = __uint_as_float(qa.z & 0xffff0000u) + __uint_as_float(qb.z & 0xffff0000u) + bb1.y;
      c1.z = __uint_as_float(qa.w << 16) + __uint_as_float(qb.w << 16) + bb1.z;
      c1.w = __uint_as_float(qa.w & 0xffff0000u) + __uint_as_float(qb.w & 0xffff0000u) + bb1.w;
      const float* pw = pcw + n * 64 + o * 8;
      float4 w0 = *(const float4*)pw;
      float4 w1 = *(const float4*)(pw + 4);
      const float myu = pcb[n * 8 + o] + dot8v(w0, w1, c0, c1);
      const float partner = __shfl_xor(myu, 1, 64);
      if (!(o & 1)) {
        unsigned pk = h16(myu) | (h16(partner) << 16);
        u2[n * 128 + b * 4 + (o >> 1)] = pk;
      }
    }
  }
}

// ---- routing pass, LDS-staged f16 W, fdot2; zero_v=1 -> c == 1/8 exactly ----
__global__ __launch_bounds__(256, 4) void caps_accb2(const unsigned* __restrict__ u2,
    const u16* __restrict__ Wbs, const float* __restrict__ vsum,
    float* __restrict__ Spart, int zero_v) {
  __shared__ u16 Ws[16 * 1088];
  const int tid = threadIdx.x;
  const int b = tid >> 3, e = tid & 7;
  const int n0 = blockIdx.x * 16;

  const u16* gsrc = Wbs + n0 * 1088;
#pragma unroll
  for (int k = 0; k < 9; k++) {
    const int idx = k * 256 + tid;
    if (idx < 2176) GLDS16(gsrc + idx * 8, Ws + idx * 8);
  }

  float4 V0 = make_float4(0.f, 0.f, 0.f, 0.f), V1 = V0, V2 = V0, V3 = V0;
  if (!zero_v) {
    const float* vp = vsum + tid * 16;
    V0 = *(const float4*)vp;
    V1 = *(const float4*)(vp + 4);
    V2 = *(const float4*)(vp + 8);
    V3 = *(const float4*)(vp + 12);
  }
  float s0 = 0.f, s1 = 0.f, s2 = 0.f, s3 = 0.f, s4 = 0.f, s5 = 0.f, s6 = 0.f, s7 = 0.f;
  float s8 = 0.f, s9 = 0.f, s10 = 0.f, s11 = 0.f, s12 = 0.f, s13 = 0.f, s14 = 0.f, s15 = 0.f;

  __syncthreads();

  for (int it = 0; it < 16; it++) {
    const int n = n0 + it;
    const uint4 up = *(const uint4*)(u2 + n * 128 + b * 4);
    const u16* Wn = Ws + it * 1088 + e * 136;
    float h0, h1, h2, h3, h4, h5, h6, h7, h8, h9, h10, h11, h12, h13, h14, h15;
#define ROW(o, H) { uint4 w = *(const uint4*)(Wn + (o) * 8); H = dotrow16(w, up); }
    ROW(0, h0)   ROW(1, h1)   ROW(2, h2)   ROW(3, h3)
    ROW(4, h4)   ROW(5, h5)   ROW(6, h6)   ROW(7, h7)
    ROW(8, h8)   ROW(9, h9)   ROW(10, h10) ROW(11, h11)
    ROW(12, h12) ROW(13, h13) ROW(14, h14) ROW(15, h15)
#undef ROW
    float c;
    if (zero_v) {
      c = 0.125f;
    } else {
      float blog = h0 * V0.x;
      blog = fmaf(h1, V0.y, blog);  blog = fmaf(h2, V0.z, blog);  blog = fmaf(h3, V0.w, blog);
      blog = fmaf(h4, V1.x, blog);  blog = fmaf(h5, V1.y, blog);  blog = fmaf(h6, V1.z, blog);
      blog = fmaf(h7, V1.w, blog);  blog = fmaf(h8, V2.x, blog);  blog = fmaf(h9, V2.y, blog);
      blog = fmaf(h10, V2.z, blog); blog = fmaf(h11, V2.w, blog); blog = fmaf(h12, V3.x, blog);
      blog = fmaf(h13, V3.y, blog); blog = fmaf(h14, V3.z, blog); blog = fmaf(h15, V3.w, blog);
      float m = blog;
      m = fmaxf(m, __shfl_xor(m, 1, 64));
      m = fmaxf(m, __shfl_xor(m, 2, 64));
      m = fmaxf(m, __shfl_xor(m, 4, 64));
      float ex = __expf(blog - m);
      float ss = ex;
      ss += __shfl_xor(ss, 1, 64);
      ss += __shfl_xor(ss, 2, 64);
      ss += __shfl_xor(ss, 4, 64);
      c = ex / ss;
    }
    s0 = fmaf(c, h0, s0);   s1 = fmaf(c, h1, s1);   s2 = fmaf(c, h2, s2);   s3 = fmaf(c, h3, s3);
    s4 = fmaf(c, h4, s4);   s5 = fmaf(c, h5, s5);   s6 = fmaf(c, h6, s6);   s7 = fmaf(c, h7, s7);
    s8 = fmaf(c, h8, s8);   s9 = fmaf(c, h9, s9);   s10 = fmaf(c, h10, s10); s11 = fmaf(c, h11, s11);
    s12 = fmaf(c, h12, s12); s13 = fmaf(c, h13, s13); s14 = fmaf(c, h14, s14); s15 = fmaf(c, h15, s15);
  }
  float* Sp = Spart + blockIdx.x * 4096 + tid * 16;
  *(float4*)(Sp + 0)  = make_float4(s0, s1, s2, s3);
  *(float4*)(Sp + 4)  = make_float4(s4, s5, s6, s7);
  *(float4*)(Sp + 8)  = make_float4(s8, s9, s10, s11);
  *(float4*)(Sp + 12) = make_float4(s12, s13, s14, s15);
}

// 1250 partials -> 25 partials (no atomics, no memset); grid (16,25)
__global__ void caps_redB(const float* __restrict__ Spart, float* __restrict__ Sp2) {
  const int j = blockIdx.x * 256 + threadIdx.x;
  const int r0 = blockIdx.y * 50;
  float a0 = 0.f, a1 = 0.f;
  for (int r = 0; r < 50; r += 2) {
    a0 += Spart[(r0 + r) * 4096 + j];
    a1 += Spart[(r0 + r + 1) * 4096 + j];
  }
  Sp2[blockIdx.y * 4096 + j] = a0 + a1;
}

// sum 25 partials -> squash -> vsum (set/add)
__global__ void caps_v2(const float* __restrict__ Sp2, float* __restrict__ vsum, int add) {
  const int t = threadIdx.x;
  float4 a0 = make_float4(0.f, 0.f, 0.f, 0.f), a1 = a0, a2 = a0, a3 = a0;
  for (int r = 0; r < 25; r++) {
    const float* sp = Sp2 + r * 4096 + t * 16;
    const float4 q0 = *(const float4*)sp;
    const float4 q1 = *(const float4*)(sp + 4);
    const float4 q2 = *(const float4*)(sp + 8);
    const float4 q3 = *(const float4*)(sp + 12);
    a0.x += q0.x; a0.y += q0.y; a0.z += q0.z; a0.w += q0.w;
    a1.x += q1.x; a1.y += q1.y; a1.z += q1.z; a1.w += q1.w;
    a2.x += q2.x; a2.y += q2.y; a2.z += q2.z; a2.w += q2.w;
    a3.x += q3.x; a3.y += q3.y; a3.z += q3.z; a3.w += q3.w;
  }
  float n2 = a0.x * a0.x;
  n2 = fmaf(a0.y, a0.y, n2); n2 = fmaf(a0.z, a0.z, n2); n2 = fmaf(a0.w, a0.w, n2);
  n2 = fmaf(a1.x, a1.x, n2); n2 = fmaf(a1.y, a1.y, n2); n2 = fmaf(a1.z, a1.z, n2); n2 = fmaf(a1.w, a1.w, n2);
  n2 = fmaf(a2.x, a2.x, n2); n2 = fmaf(a2.y, a2.y, n2); n2 = fmaf(a2.z, a2.z, n2); n2 = fmaf(a2.w, a2.w, n2);
  n2 = fmaf(a3.x, a3.x, n2); n2 = fmaf(a3.y, a3.y, n2); n2 = fmaf(a3.z, a3.z, n2); n2 = fmaf(a3.w, a3.w, n2);
  const float n = sqrtf(n2);
  const float scale = n2 / ((1.f + n2) * (n + 1e-8f));
  float* vp = vsum + t * 16;
  float4 o0, o1, o2, o3;
  if (add) {
    o0 = *(float4*)(vp + 0); o1 = *(float4*)(vp + 4); o2 = *(float4*)(vp + 8); o3 = *(float4*)(vp + 12);
  } else {
    o0 = make_float4(0.f, 0.f, 0.f, 0.f); o1 = o0; o2 = o0; o3 = o0;
  }
  o0.x = fmaf(a0.x, scale, o0.x); o0.y = fmaf(a0.y, scale, o0.y);
  o0.z = fmaf(a0.z, scale, o0.z); o0.w = fmaf(a0.w, scale, o0.w);
  o1.x = fmaf(a1.x, scale, o1.x); o1.y = fmaf(a1.y, scale, o1.y);
  o1.z = fmaf(a1.z, scale, o1.z); o1.w = fmaf(a1.w, scale, o1.w);
  o2.x = fmaf(a2.x, scale, o2.x); o2.y = fmaf(a2.y, scale, o2.y);
  o2.z = fmaf(a2.z, scale, o2.z); o2.w = fmaf(a2.w, scale, o2.w);
  o3.x = fmaf(a3.x, scale, o3.x); o3.y = fmaf(a3.y, scale, o3.y);
  o3.z = fmaf(a3.z, scale, o3.z); o3.w = fmaf(a3.w, scale, o3.w);
  *(float4*)(vp + 0) = o0; *(float4*)(vp + 4) = o1;
  *(float4*)(vp + 8) = o2; *(float4*)(vp + 12) = o3;
}

// sum 25 partials -> out = ||squash(S)||
__global__ void caps_out2(const float* __restrict__ Sp2, float* __restrict__ out) {
  const int t = threadIdx.x;
  float4 a0 = make_float4(0.f, 0.f, 0.f, 0.f), a1 = a0, a2 = a0, a3 = a0;
  for (int r = 0; r < 25; r++) {
    const float* sp = Sp2 + r * 4096 + t * 16;
    const float4 q0 = *(const float4*)sp;
    const float4 q1 = *(const float4*)(sp + 4);
    const float4 q2 = *(const float4*)(sp + 8);
    const float4 q3 = *(const float4*)(sp + 12);
    a0.x += q0.x; a0.y += q0.y; a0.z += q0.z; a0.w += q0.w;
    a1.x += q1.x; a1.y += q1.y; a1.z += q1.z; a1.w += q1.w;
    a2.x += q2.x; a2.y += q2.y; a2.z += q2.z; a2.w += q2.w;
    a3.x += q3.x; a3.y += q3.y; a3.z += q3.z; a3.w += q3.w;
  }
  float n2 = a0.x * a0.x;
  n2 = fmaf(a0.y, a0.y, n2); n2 = fmaf(a0.z, a0.z, n2); n2 = fmaf(a0.w, a0.w, n2);
  n2 = fmaf(a1.x, a1.x, n2); n2 = fmaf(a1.y, a1.y, n2); n2 = fmaf(a1.z, a1.z, n2); n2 = fmaf(a1.w, a1.w, n2);
  n2 = fmaf(a2.x, a2.x, n2); n2 = fmaf(a2.y, a2.y, n2); n2 = fmaf(a2.z, a2.z, n2); n2 = fmaf(a2.w, a2.w, n2);
  n2 = fmaf(a3.x, a3.x, n2); n2 = fmaf(a3.y, a3.y, n2); n2 = fmaf(a3.z, a3.z, n2); n2 = fmaf(a3.w, a3.w, n2);
  const float n = sqrtf(n2);
  out[t] = n * n2 / ((1.f + n2) * (n + 1e-8f));
}

extern "C" void kernel_launch(void* const* d_in, const int* in_sizes, int n_in,
                              void* d_out, int out_size, void* d_ws, size_t ws_size,
                              hipStream_t stream) {
  const float* x   = (const float*)d_in[0];
  const float* w1  = (const float*)d_in[1];
  const float* b1  = (const float*)d_in[2];
  const float* w2  = (const float*)d_in[3];
  const float* b2  = (const float*)d_in[4];
  const float* w3  = (const float*)d_in[5];
  const float* b3  = (const float*)d_in[6];
  const float* pcw = (const float*)d_in[7];
  const float* pcb = (const float*)d_in[8];
  const float* W   = (const float*)d_in[9];
  float* out = (float*)d_out;

  char* ws = (char*)d_ws;

  // Phase 1 (convs):
  u16*   x1p = (u16*)(ws + 0);           // 14,745,600 (dead after conv3)
  u16*   A2  = (u16*)(ws + 14745600);    //  4,718,592 (dead after conv2)
  u16*   A3  = (u16*)(ws + 19464192);    //    262,144 (dead after conv3)
  u16*   y   = (u16*)(ws + 19726336);    // 10,240,000 (dead after conv3)
  u16*   P   = (u16*)(ws + 29966336);    // 40,960,000 (dead after conv2_red)
  // Phase 2 (caps):
  u16*   P3  = (u16*)(ws + 43520000);    // 20,480,000 conv3 bf16 partials
  u16*   Wbs = (u16*)(ws + 0);           // 43,520,000 f16 (written after conv3)
  float* Spart = (float*)(ws + 43520000);// 20,480,000 (reuses P3 after prep_caps)
  unsigned* u2 = (unsigned*)(ws + 64000000); // 10,240,000
  float* Sp2 = (float*)(ws + 74240000);  // 409,600
  float* vs  = (float*)(ws + 74649600);  // 16,384

  hipMemsetAsync(x1p, 0, 14745600, stream);

  prep_conv1<<<1184, 256, 0, stream>>>(w2, w3, A2, A3, x, w1, b1, x1p);
  conv2_gemm<<<252, 512, 0, stream>>>(A2, x1p, P);
  conv2_red<<<5000, 256, 0, stream>>>(P, b2, y);
  conv3_gemm<<<dim3(2, 157, 2), 256, 0, stream>>>(A3, x1p, y, P3);
  prep_caps<<<12500, 256, 0, stream>>>(W, Wbs, P3, b3, pcw, pcb, u2);

  for (int pass = 0; pass < 3; pass++) {
    caps_accb2<<<1250, 256, 0, stream>>>(u2, Wbs, vs, Spart, pass == 0 ? 1 : 0);
    caps_redB<<<dim3(16, 25), 256, 0, stream>>>(Spart, Sp2);
    if (pass == 0)      caps_v2<<<1, 256, 0, stream>>>(Sp2, vs, 0);
    else if (pass == 1) caps_v2<<<1, 256, 0, stream>>>(Sp2, vs, 1);
    else                caps_out2<<<1, 256, 0, stream>>>(Sp2, out);
  }
}

// Round 5
// 424.105 us; speedup vs baseline: 1.0424x; 1.0424x over previous
//
#include <hip/hip_runtime.h>
#include <hip/hip_fp16.h>

typedef unsigned short u16;
typedef __attribute__((ext_vector_type(8))) short bf16x8;
typedef __attribute__((ext_vector_type(4))) float floatx4;
typedef __attribute__((ext_vector_type(2))) _Float16 half2v;

#define NPIX 625
#define NCAPS 20000
#define K2 9216

__device__ __forceinline__ u16 f2bf(float f) {
  unsigned u = __float_as_uint(f);
  return (u16)((u + 0x7fffu + ((u >> 16) & 1u)) >> 16);
}

__device__ __forceinline__ unsigned h16(float f) {
  union { _Float16 h; u16 b; } c;
  c.h = (_Float16)f;
  return (unsigned)c.b;
}

__device__ __forceinline__ half2v as_h2(unsigned u) {
  union { unsigned i; half2v h; } c;
  c.i = u;
  return c.h;
}

__device__ __forceinline__ float dot2f(unsigned a, unsigned b, float c) {
#if __has_builtin(__builtin_amdgcn_fdot2)
  return __builtin_amdgcn_fdot2(as_h2(a), as_h2(b), c, false);
#else
  half2v x = as_h2(a), y = as_h2(b);
  return fmaf((float)x[1], (float)y[1], fmaf((float)x[0], (float)y[0], c));
#endif
}

__device__ __forceinline__ float dotrow16(uint4 w, uint4 u) {
  float s = dot2f(w.x, u.x, 0.f);
  s = dot2f(w.y, u.y, s);
  s = dot2f(w.z, u.z, s);
  s = dot2f(w.w, u.w, s);
  return s;
}

__device__ __forceinline__ float dot8v(float4 a0, float4 a1, float4 b0, float4 b1) {
  float s = a0.x * b0.x;
  s = fmaf(a0.y, b0.y, s); s = fmaf(a0.z, b0.z, s); s = fmaf(a0.w, b0.w, s);
  s = fmaf(a1.x, b1.x, s); s = fmaf(a1.y, b1.y, s);
  s = fmaf(a1.z, b1.z, s); s = fmaf(a1.w, b1.w, s);
  return s;
}

#define GLDS16(g, l) __builtin_amdgcn_global_load_lds( \
    (const __attribute__((address_space(1))) void*)(g), \
    (__attribute__((address_space(3))) void*)(l), 16, 0, 0)

#define MFMA16(a, b, c) __builtin_amdgcn_mfma_f32_16x16x32_bf16((a), (b), (c), 0, 0, 0)

// ---------- merged: w2/w3 prep (blocks 0..383) + conv1 (blocks 384..1183) ----------
// w2 pack: A2n[(kt*256 + oc)*2304 + tl*256 + c], tap g = kt*9 + tl.
__global__ void prep_conv1(const float* __restrict__ w2, const float* __restrict__ w3,
                           u16* __restrict__ A2c, u16* __restrict__ A3,
                           const float* __restrict__ x, const float* __restrict__ w1,
                           const float* __restrict__ b1, u16* __restrict__ x1p) {
  if (blockIdx.x < 256) {
    const int oc = blockIdx.x, c = threadIdx.x;
    const float* src = w2 + (oc * 256 + c) * 36;
    float v[36];
#pragma unroll
    for (int k = 0; k < 9; k++) {
      const float4 q = *(const float4*)(src + k * 4);
      v[k * 4 + 0] = q.x; v[k * 4 + 1] = q.y; v[k * 4 + 2] = q.z; v[k * 4 + 3] = q.w;
    }
#pragma unroll
    for (int g = 0; g < 36; g++) {
      const int ktp = g / 9, tl = g % 9;
      A2c[(ktp * 256 + oc) * 2304 + tl * 256 + c] = f2bf(v[g]);
    }
  } else if (blockIdx.x < 384) {
    const int j = (blockIdx.x - 256) * 1024 + threadIdx.x * 4;
    const float4 q = *(const float4*)(w3 + j);
    ushort4 p;
    p.x = f2bf(q.x); p.y = f2bf(q.y); p.z = f2bf(q.z); p.w = f2bf(q.w);
    *(ushort4*)(A3 + j) = p;
  } else {
    const int blk = blockIdx.x - 384;     // 800 = 32 b * 25 rows
    const int b = blk / 25, i = blk % 25;
    const int f = threadIdx.x;
    float wreg[36];
#pragma unroll
    for (int k = 0; k < 36; k++) wreg[k] = w1[f * 36 + k];
    float bias = b1[f];
    const float* xb = x + b * 54 * 54 + (2 * i) * 54;
    for (int j = 0; j < 25; j++) {
      float acc = bias;
#pragma unroll
      for (int ki = 0; ki < 6; ki++)
#pragma unroll
        for (int kj = 0; kj < 6; kj++)
          acc = fmaf(xb[ki * 54 + 2 * j + kj], wreg[ki * 6 + kj], acc);
      x1p[(((b * 30 + i + 2) * 30) + (j + 2)) * 256 + f] = f2bf(fmaxf(acc, 0.f));
    }
  }
}

// ---------- conv2 implicit GEMM, BM=256 x BN=320, BK=64, split-K=4 ----------
// 8 waves (2m x 4n), wave tile 128x80. 2-buffer LDS, 252 blocks = 1 round.
// ROUND-5 STRUCTURE: intra-wave MFMA||LDS overlap. One barrier + one vmcnt(0)
// per K-step. Four regions fenced by sched_barrier(0) only; each region's
// ds_reads (for the NEXT region) share a barrier-free window with 20 MFMAs that
// have no dependence on them -> wave issues reads non-blocking, matrix pipe
// covers LDS latency. acc lives in AGPRs (unified file), operand frags double-
// buffered (+36 VGPR). Race ledger: all Cur reads consumed by R4's in-order
// lgkm waits before the end barrier; staging of t+2 into Cur only after it;
// preload reads the buffer validated by per-wave vmcnt(0)+barrier.
__global__ __launch_bounds__(512, 1) void conv2_gemm(const u16* __restrict__ A2n,
    const u16* __restrict__ x1p, u16* __restrict__ P) {
  // per buffer: A = 256x64 u16 (0..16383), B = 320x64 u16 (16384..36863)
  __shared__ __align__(16) u16 lds[2][36864];
  const int tid = threadIdx.x;
  const int lane = tid & 63, wave = tid >> 6;
  // XCD swizzle (kept from round 4: -11% FETCH, neutral dur)
  const int bid = blockIdx.x;                    // 0..251
  const int xcd = bid & 7, idx = bid >> 3;
  const int kt = xcd & 3;
  const int ntile = (xcd >> 2) ? (32 + idx) : idx;
  const int wm = wave & 1, wn = wave >> 1;       // wm: oc 128-half, wn: n 80-block
  const int lrow = lane & 15, kg = lane >> 4;

  const int trow = tid >> 3;                     // staging row within a 64-row group
  const int xoff = 8 * ((tid & 7) ^ (trow & 7)); // inverse-swizzle on global source
  const u16* aSrc = A2n + (kt * 256 + trow) * 2304 + xoff;
  const int nb = ntile * 320;                    // 63*320 = 20160, clamp at 20000
  auto pixrow = [&](int r) {
    int n = nb + r;
    if (n > NCAPS - 1) n = NCAPS - 1;
    const int b = n / NPIX, p = n % NPIX;
    const int i = p / 25, j = p % 25;
    return ((b * 30 + i) * 30 + j) * 256;
  };
  const u16* bSrc0 = x1p + pixrow(trow) + xoff;
  const u16* bSrc1 = x1p + pixrow(64 + trow) + xoff;
  const u16* bSrc2 = x1p + pixrow(128 + trow) + xoff;
  const u16* bSrc3 = x1p + pixrow(192 + trow) + xoff;
  const u16* bSrc4 = x1p + pixrow(256 + trow) + xoff;

  auto stageA = [&](u16* L, int tt) {            // 4 loads: A rows 0..255
    const u16* a = aSrc + tt * 64;
    GLDS16(a,               L + tid * 8);
    GLDS16(a + 64 * 2304,   L + 4096 + tid * 8);
    GLDS16(a + 128 * 2304,  L + 8192 + tid * 8);
    GLDS16(a + 192 * 2304,  L + 12288 + tid * 8);
  };
  auto stageB = [&](u16* L, int tt) {            // 5 loads: B rows 0..319
    const int g = kt * 9 + (tt >> 2);
    const int boff = ((g / 6) * 30 + (g % 6)) * 256 + (tt & 3) * 64;
    GLDS16(bSrc0 + boff, L + 16384 + tid * 8);
    GLDS16(bSrc1 + boff, L + 20480 + tid * 8);
    GLDS16(bSrc2 + boff, L + 24576 + tid * 8);
    GLDS16(bSrc3 + boff, L + 28672 + tid * 8);
    GLDS16(bSrc4 + boff, L + 32768 + tid * 8);
  };

  floatx4 acc[8][5] = {};
  const int jx0 = 8 * (kg ^ (lrow & 7));         // swizzled 16B-slot, k-half 0
  const int jx1 = 8 * ((4 + kg) ^ (lrow & 7));   // k-half 1
  const int arow = wm * 128 + lrow;
  const int brow = wn * 80 + lrow;

  auto rdA = [&](const u16* L, int row, int jx) {
    return *(const bf16x8*)(L + row * 64 + jx);
  };
  auto rdB = [&](const u16* L, int row, int jx) {
    return *(const bf16x8*)(L + 16384 + row * 64 + jx);
  };

  // ---- prologue: stage tile 0, drain, preload kh0 operands ----
  stageA(lds[0], 0);
  stageB(lds[0], 0);
  asm volatile("s_waitcnt vmcnt(0)" ::: "memory");
  __builtin_amdgcn_s_barrier();

  bf16x8 af[4], bvA[5];
#pragma unroll
  for (int fm = 0; fm < 4; fm++) af[fm] = rdA(lds[0], arow + fm * 16, jx0);
#pragma unroll
  for (int fn = 0; fn < 5; fn++) bvA[fn] = rdB(lds[0], brow + fn * 16, jx0);

  for (int t = 0; t < 36; t++) {
    u16* Cur = lds[t & 1];
    u16* Oth = lds[(t & 1) ^ 1];
    const bool st = (t < 35);

    // ---- R1: stage t+1 || read (A kh0-hi, B kh1) || MFMA af x bvA ----
    if (st) { stageA(Oth, t + 1); stageB(Oth, t + 1); }
    bf16x8 ag[4], bvB[5];
#pragma unroll
    for (int fm = 0; fm < 4; fm++) ag[fm] = rdA(Cur, arow + 64 + fm * 16, jx0);
#pragma unroll
    for (int fn = 0; fn < 5; fn++) bvB[fn] = rdB(Cur, brow + fn * 16, jx1);
#pragma unroll
    for (int fm = 0; fm < 4; fm++)
#pragma unroll
      for (int fn = 0; fn < 5; fn++)
        acc[fm][fn] = MFMA16(af[fm], bvA[fn], acc[fm][fn]);
    __builtin_amdgcn_sched_barrier(0);

    // ---- R2: read A kh1-lo || MFMA ag x bvA ----
    bf16x8 af2[4];
#pragma unroll
    for (int fm = 0; fm < 4; fm++) af2[fm] = rdA(Cur, arow + fm * 16, jx1);
#pragma unroll
    for (int fm = 0; fm < 4; fm++)
#pragma unroll
      for (int fn = 0; fn < 5; fn++)
        acc[4 + fm][fn] = MFMA16(ag[fm], bvA[fn], acc[4 + fm][fn]);
    __builtin_amdgcn_sched_barrier(0);

    // ---- R3: read A kh1-hi || MFMA af2 x bvB ----
    bf16x8 ag2[4];
#pragma unroll
    for (int fm = 0; fm < 4; fm++) ag2[fm] = rdA(Cur, arow + 64 + fm * 16, jx1);
#pragma unroll
    for (int fm = 0; fm < 4; fm++)
#pragma unroll
      for (int fn = 0; fn < 5; fn++)
        acc[fm][fn] = MFMA16(af2[fm], bvB[fn], acc[fm][fn]);
    __builtin_amdgcn_sched_barrier(0);

    // ---- R4: MFMA ag2 x bvB ----
#pragma unroll
    for (int fm = 0; fm < 4; fm++)
#pragma unroll
      for (int fn = 0; fn < 5; fn++)
        acc[4 + fm][fn] = MFMA16(ag2[fm], bvB[fn], acc[4 + fm][fn]);

    // ---- K-step boundary: validate t+1, preload its kh0 operands ----
    if (st) {
      asm volatile("s_waitcnt vmcnt(0)" ::: "memory");
      __builtin_amdgcn_s_barrier();
#pragma unroll
      for (int fm = 0; fm < 4; fm++) af[fm] = rdA(Oth, arow + fm * 16, jx0);
#pragma unroll
      for (int fn = 0; fn < 5; fn++) bvA[fn] = rdB(Oth, brow + fn * 16, jx0);
    }
  }

  u16* Pk = P + kt * 5120000;
#pragma unroll
  for (int fn = 0; fn < 5; fn++) {
    const int n = nb + wn * 80 + fn * 16 + lrow;
    if (n < NCAPS) {
#pragma unroll
      for (int fm = 0; fm < 8; fm++) {
        const int oc = wm * 128 + fm * 16 + kg * 4;
        ushort4 pk;
        pk.x = f2bf(acc[fm][fn][0]);
        pk.y = f2bf(acc[fm][fn][1]);
        pk.z = f2bf(acc[fm][fn][2]);
        pk.w = f2bf(acc[fm][fn][3]);
        *(ushort4*)(Pk + n * 256 + oc) = pk;
      }
    }
  }
}

// ---------- conv2 split-K reduce: y = bf16(relu(sum P[0..3] + bias)) ----------
__global__ void conv2_red(const u16* __restrict__ P, const float* __restrict__ bias2,
                          u16* __restrict__ y) {
  const int idx = blockIdx.x * 256 + threadIdx.x;
  const ushort4 p0 = *(const ushort4*)(P + idx * 4);
  const ushort4 p1 = *(const ushort4*)(P + 5120000 + idx * 4);
  const ushort4 p2 = *(const ushort4*)(P + 10240000 + idx * 4);
  const ushort4 p3 = *(const ushort4*)(P + 15360000 + idx * 4);
  const float4 bs = *(const float4*)(bias2 + ((idx * 4) & 255));
  auto bf = [](unsigned v) { return __uint_as_float(v << 16); };
  float sx = bf(p0.x) + bf(p1.x) + bf(p2.x) + bf(p3.x) + bs.x;
  float sy = bf(p0.y) + bf(p1.y) + bf(p2.y) + bf(p3.y) + bs.y;
  float sz = bf(p0.z) + bf(p1.z) + bf(p2.z) + bf(p3.z) + bs.z;
  float sw = bf(p0.w) + bf(p1.w) + bf(p2.w) + bf(p3.w) + bs.w;
  ushort4 pk;
  pk.x = f2bf(fmaxf(sx, 0.f));
  pk.y = f2bf(fmaxf(sy, 0.f));
  pk.z = f2bf(fmaxf(sz, 0.f));
  pk.w = f2bf(fmaxf(sw, 0.f));
  *(ushort4*)(y + idx * 4) = pk;
}

// ---------- conv3 1x1 GEMM, split-K=2 (kt0: x1 half, kt1: y half) ----------
__global__ __launch_bounds__(256) void conv3_gemm(const u16* __restrict__ A3,
    const u16* __restrict__ x1p, const u16* __restrict__ y, u16* __restrict__ P3) {
  __shared__ u16 As[128 * 32];
  __shared__ u16 Bs[128 * 32];
  const int tid = threadIdx.x;
  const int lane = tid & 63, wave = tid >> 6;
  const int mtile = blockIdx.x, ntile = blockIdx.y, kt = blockIdx.z;

  const int seg0 = tid, seg1 = tid + 256;
  const u16* ga0 = A3 + (mtile * 128 + (seg0 >> 2)) * 512 + (seg0 & 3) * 8 + kt * 256;
  const u16* ga1 = A3 + (mtile * 128 + (seg1 >> 2)) * 512 + (seg1 & 3) * 8 + kt * 256;

  auto mkbase = [&](int seg) {
    int n = ntile * 128 + (seg >> 2);
    if (n > NCAPS - 1) n = NCAPS - 1;
    if (kt == 0) {
      int b = n / NPIX, p = n % NPIX;
      int i = p / 25, j = p % 25;
      return x1p + ((b * 30 + i + 2) * 30 + (j + 2)) * 256 + (seg & 3) * 8;
    }
    return y + n * 256 + (seg & 3) * 8;
  };
  const u16* gs0 = mkbase(seg0);
  const u16* gs1 = mkbase(seg1);

  floatx4 acc[4][4] = {};
  const int wm = wave & 1, wn = wave >> 1;
  const int lrow = lane & 15, kgrp = lane >> 4;

  for (int kc = 0; kc < 8; kc++) {
    GLDS16(ga0 + kc * 32, As + seg0 * 8);
    GLDS16(ga1 + kc * 32, As + seg1 * 8);
    GLDS16(gs0 + kc * 32, Bs + seg0 * 8);
    GLDS16(gs1 + kc * 32, Bs + seg1 * 8);
    __syncthreads();
    bf16x8 af[4], bfr[4];
#pragma unroll
    for (int tt = 0; tt < 4; tt++) {
      af[tt]  = *(const bf16x8*)(As + (wm * 64 + tt * 16 + lrow) * 32 + kgrp * 8);
      bfr[tt] = *(const bf16x8*)(Bs + (wn * 64 + tt * 16 + lrow) * 32 + kgrp * 8);
    }
#pragma unroll
    for (int tm = 0; tm < 4; tm++)
#pragma unroll
      for (int tn = 0; tn < 4; tn++)
        acc[tm][tn] = __builtin_amdgcn_mfma_f32_16x16x32_bf16(af[tm], bfr[tn], acc[tm][tn], 0, 0, 0);
    __syncthreads();
  }

  u16* Pk = P3 + kt * 5120000;
  const int nb = ntile * 128 + wn * 64;
  const int fb = mtile * 128 + wm * 64 + kgrp * 4;
#pragma unroll
  for (int tn = 0; tn < 4; tn++) {
    int n = nb + tn * 16 + lrow;
    if (n < NCAPS) {
#pragma unroll
      for (int tm = 0; tm < 4; tm++) {
        int f0 = fb + tm * 16;
        ushort4 pk;
        pk.x = f2bf(acc[tm][tn][0]);
        pk.y = f2bf(acc[tm][tn][1]);
        pk.z = f2bf(acc[tm][tn][2]);
        pk.w = f2bf(acc[tm][tn][3]);
        *(ushort4*)(Pk + n * 256 + f0) = pk;
      }
    }
  }
}

// ---------- merged: W->f16 swizzle (blocks 0..9999) + u (blocks 10000..12499) ----------
__global__ void prep_caps(const float* __restrict__ W, u16* __restrict__ Wbs,
                          const u16* __restrict__ P3, const float* __restrict__ b3,
                          const float* __restrict__ pcw, const float* __restrict__ pcb,
                          unsigned* __restrict__ u2) {
  const int tid = threadIdx.x;
  if (blockIdx.x < 10000) {
    int r = blockIdx.x * 256 + tid;
    int n = r >> 7, eo = r & 127;
    int e = eo >> 4, o = eo & 15;
    const float* src = W + n * 1024 + eo * 8;
    const float4 v0 = *(const float4*)src;
    const float4 v1 = *(const float4*)(src + 4);
    u16* dst = Wbs + n * 1088 + e * 136 + o * 8;
    ushort4 p0, p1;
    p0.x = (u16)h16(v0.x); p0.y = (u16)h16(v0.y); p0.z = (u16)h16(v0.z); p0.w = (u16)h16(v0.w);
    p1.x = (u16)h16(v1.x); p1.y = (u16)h16(v1.y); p1.z = (u16)h16(v1.z); p1.w = (u16)h16(v1.w);
    *(ushort4*)dst = p0;
    *(ushort4*)(dst + 4) = p1;
  } else {
    const int blk = blockIdx.x - 10000;
    const int b = tid >> 3, o = tid & 7;
    for (int k = 0; k < 8; k++) {
      const int n = blk * 8 + k;
      const int g = n / NPIX, p = n % NPIX;
      const u16* pa = P3 + ((b * NPIX + p) * 256 + g * 8);
      const uint4 qa = *(const uint4*)pa;
      const uint4 qb = *(const uint4*)(pa + 5120000);
      const float* bp = b3 + g * 8;
      const float4 bb0 = *(const float4*)bp;
      const float4 bb1 = *(const float4*)(bp + 4);
      float4 c0, c1;
      c0.x = __uint_as_float(qa.x << 16) + __uint_as_float(qb.x << 16) + bb0.x;
      c0.y = __uint_as_float(qa.x & 0xffff0000u) + __uint_as_float(qb.x & 0xffff0000u) + bb0.y;
      c0.z = __uint_as_float(qa.y << 16) + __uint_as_float(qb.y << 16) + bb0.z;
      c0.w = __uint_as_float(qa.y & 0xffff0000u) + __uint_as_float(qb.y & 0xffff0000u) + bb0.w;
      c1.x = __uint_as_float(qa.z << 16) + __uint_as_float(qb.z << 16) + bb1.x;
      c1.y = __uint_as_float(qa.z & 0xffff0000u) + __uint_as_float(qb.z & 0xffff0000u) + bb1.y;
      c1.z = __uint_as_float(qa.w << 16) + __uint_as_float(qb.w << 16) + bb1.z;
      c1.w = __uint_as_float(qa.w & 0xffff0000u) + __uint_as_float(qb.w & 0xffff0000u) + bb1.w;
      const float* pw = pcw + n * 64 + o * 8;
      float4 w0 = *(const float4*)pw;
      float4 w1 = *(const float4*)(pw + 4);
      const float myu = pcb[n * 8 + o] + dot8v(w0, w1, c0, c1);
      const float partner = __shfl_xor(myu, 1, 64);
      if (!(o & 1)) {
        unsigned pk = h16(myu) | (h16(partner) << 16);
        u2[n * 128 + b * 4 + (o >> 1)] = pk;
      }
    }
  }
}

// ---- routing pass, LDS-staged f16 W, fdot2; zero_v=1 -> c == 1/8 exactly ----
__global__ __launch_bounds__(256, 4) void caps_accb2(const unsigned* __restrict__ u2,
    const u16* __restrict__ Wbs, const float* __restrict__ vsum,
    float* __restrict__ Spart, int zero_v) {
  __shared__ u16 Ws[16 * 1088];
  const int tid = threadIdx.x;
  const int b = tid >> 3, e = tid & 7;
  const int n0 = blockIdx.x * 16;

  const u16* gsrc = Wbs + n0 * 1088;
#pragma unroll
  for (int k = 0; k < 9; k++) {
    const int idx = k * 256 + tid;
    if (idx < 2176) GLDS16(gsrc + idx * 8, Ws + idx * 8);
  }

  float4 V0 = make_float4(0.f, 0.f, 0.f, 0.f), V1 = V0, V2 = V0, V3 = V0;
  if (!zero_v) {
    const float* vp = vsum + tid * 16;
    V0 = *(const float4*)vp;
    V1 = *(const float4*)(vp + 4);
    V2 = *(const float4*)(vp + 8);
    V3 = *(const float4*)(vp + 12);
  }
  float s0 = 0.f, s1 = 0.f, s2 = 0.f, s3 = 0.f, s4 = 0.f, s5 = 0.f, s6 = 0.f, s7 = 0.f;
  float s8 = 0.f, s9 = 0.f, s10 = 0.f, s11 = 0.f, s12 = 0.f, s13 = 0.f, s14 = 0.f, s15 = 0.f;

  __syncthreads();

  for (int it = 0; it < 16; it++) {
    const int n = n0 + it;
    const uint4 up = *(const uint4*)(u2 + n * 128 + b * 4);
    const u16* Wn = Ws + it * 1088 + e * 136;
    float h0, h1, h2, h3, h4, h5, h6, h7, h8, h9, h10, h11, h12, h13, h14, h15;
#define ROW(o, H) { uint4 w = *(const uint4*)(Wn + (o) * 8); H = dotrow16(w, up); }
    ROW(0, h0)   ROW(1, h1)   ROW(2, h2)   ROW(3, h3)
    ROW(4, h4)   ROW(5, h5)   ROW(6, h6)   ROW(7, h7)
    ROW(8, h8)   ROW(9, h9)   ROW(10, h10) ROW(11, h11)
    ROW(12, h12) ROW(13, h13) ROW(14, h14) ROW(15, h15)
#undef ROW
    float c;
    if (zero_v) {
      c = 0.125f;
    } else {
      float blog = h0 * V0.x;
      blog = fmaf(h1, V0.y, blog);  blog = fmaf(h2, V0.z, blog);  blog = fmaf(h3, V0.w, blog);
      blog = fmaf(h4, V1.x, blog);  blog = fmaf(h5, V1.y, blog);  blog = fmaf(h6, V1.z, blog);
      blog = fmaf(h7, V1.w, blog);  blog = fmaf(h8, V2.x, blog);  blog = fmaf(h9, V2.y, blog);
      blog = fmaf(h10, V2.z, blog); blog = fmaf(h11, V2.w, blog); blog = fmaf(h12, V3.x, blog);
      blog = fmaf(h13, V3.y, blog); blog = fmaf(h14, V3.z, blog); blog = fmaf(h15, V3.w, blog);
      float m = blog;
      m = fmaxf(m, __shfl_xor(m, 1, 64));
      m = fmaxf(m, __shfl_xor(m, 2, 64));
      m = fmaxf(m, __shfl_xor(m, 4, 64));
      float ex = __expf(blog - m);
      float ss = ex;
      ss += __shfl_xor(ss, 1, 64);
      ss += __shfl_xor(ss, 2, 64);
      ss += __shfl_xor(ss, 4, 64);
      c = ex / ss;
    }
    s0 = fmaf(c, h0, s0);   s1 = fmaf(c, h1, s1);   s2 = fmaf(c, h2, s2);   s3 = fmaf(c, h3, s3);
    s4 = fmaf(c, h4, s4);   s5 = fmaf(c, h5, s5);   s6 = fmaf(c, h6, s6);   s7 = fmaf(c, h7, s7);
    s8 = fmaf(c, h8, s8);   s9 = fmaf(c, h9, s9);   s10 = fmaf(c, h10, s10); s11 = fmaf(c, h11, s11);
    s12 = fmaf(c, h12, s12); s13 = fmaf(c, h13, s13); s14 = fmaf(c, h14, s14); s15 = fmaf(c, h15, s15);
  }
  float* Sp = Spart + blockIdx.x * 4096 + tid * 16;
  *(float4*)(Sp + 0)  = make_float4(s0, s1, s2, s3);
  *(float4*)(Sp + 4)  = make_float4(s4, s5, s6, s7);
  *(float4*)(Sp + 8)  = make_float4(s8, s9, s10, s11);
  *(float4*)(Sp + 12) = make_float4(s12, s13, s14, s15);
}

// 1250 partials -> 25 partials (no atomics, no memset); grid (16,25)
__global__ void caps_redB(const float* __restrict__ Spart, float* __restrict__ Sp2) {
  const int j = blockIdx.x * 256 + threadIdx.x;
  const int r0 = blockIdx.y * 50;
  float a0 = 0.f, a1 = 0.f;
  for (int r = 0; r < 50; r += 2) {
    a0 += Spart[(r0 + r) * 4096 + j];
    a1 += Spart[(r0 + r + 1) * 4096 + j];
  }
  Sp2[blockIdx.y * 4096 + j] = a0 + a1;
}

// sum 25 partials -> squash -> vsum (set/add)
__global__ void caps_v2(const float* __restrict__ Sp2, float* __restrict__ vsum, int add) {
  const int t = threadIdx.x;
  float4 a0 = make_float4(0.f, 0.f, 0.f, 0.f), a1 = a0, a2 = a0, a3 = a0;
  for (int r = 0; r < 25; r++) {
    const float* sp = Sp2 + r * 4096 + t * 16;
    const float4 q0 = *(const float4*)sp;
    const float4 q1 = *(const float4*)(sp + 4);
    const float4 q2 = *(const float4*)(sp + 8);
    const float4 q3 = *(const float4*)(sp + 12);
    a0.x += q0.x; a0.y += q0.y; a0.z += q0.z; a0.w += q0.w;
    a1.x += q1.x; a1.y += q1.y; a1.z += q1.z; a1.w += q1.w;
    a2.x += q2.x; a2.y += q2.y; a2.z += q2.z; a2.w += q2.w;
    a3.x += q3.x; a3.y += q3.y; a3.z += q3.z; a3.w += q3.w;
  }
  float n2 = a0.x * a0.x;
  n2 = fmaf(a0.y, a0.y, n2); n2 = fmaf(a0.z, a0.z, n2); n2 = fmaf(a0.w, a0.w, n2);
  n2 = fmaf(a1.x, a1.x, n2); n2 = fmaf(a1.y, a1.y, n2); n2 = fmaf(a1.z, a1.z, n2); n2 = fmaf(a1.w, a1.w, n2);
  n2 = fmaf(a2.x, a2.x, n2); n2 = fmaf(a2.y, a2.y, n2); n2 = fmaf(a2.z, a2.z, n2); n2 = fmaf(a2.w, a2.w, n2);
  n2 = fmaf(a3.x, a3.x, n2); n2 = fmaf(a3.y, a3.y, n2); n2 = fmaf(a3.z, a3.z, n2); n2 = fmaf(a3.w, a3.w, n2);
  const float n = sqrtf(n2);
  const float scale = n2 / ((1.f + n2) * (n + 1e-8f));
  float* vp = vsum + t * 16;
  float4 o0, o1, o2, o3;
  if (add) {
    o0 = *(float4*)(vp + 0); o1 = *(float4*)(vp + 4); o2 = *(float4*)(vp + 8); o3 = *(float4*)(vp + 12);
  } else {
    o0 = make_float4(0.f, 0.f, 0.f, 0.f); o1 = o0; o2 = o0; o3 = o0;
  }
  o0.x = fmaf(a0.x, scale, o0.x); o0.y = fmaf(a0.y, scale, o0.y);
  o0.z = fmaf(a0.z, scale, o0.z); o0.w = fmaf(a0.w, scale, o0.w);
  o1.x = fmaf(a1.x, scale, o1.x); o1.y = fmaf(a1.y, scale, o1.y);
  o1.z = fmaf(a1.z, scale, o1.z); o1.w = fmaf(a1.w, scale, o1.w);
  o2.x = fmaf(a2.x, scale, o2.x); o2.y = fmaf(a2.y, scale, o2.y);
  o2.z = fmaf(a2.z, scale, o2.z); o2.w = fmaf(a2.w, scale, o2.w);
  o3.x = fmaf(a3.x, scale, o3.x); o3.y = fmaf(a3.y, scale, o3.y);
  o3.z = fmaf(a3.z, scale, o3.z); o3.w = fmaf(a3.w, scale, o3.w);
  *(float4*)(vp + 0) = o0; *(float4*)(vp + 4) = o1;
  *(float4*)(vp + 8) = o2; *(float4*)(vp + 12) = o3;
}

// sum 25 partials -> out = ||squash(S)||
__global__ void caps_out2(const float* __restrict__ Sp2, float* __restrict__ out) {
  const int t = threadIdx.x;
  float4 a0 = make_float4(0.f, 0.f, 0.f, 0.f), a1 = a0, a2 = a0, a3 = a0;
  for (int r = 0; r < 25; r++) {
    const float* sp = Sp2 + r * 4096 + t * 16;
    const float4 q0 = *(const float4*)sp;
    const float4 q1 = *(const float4*)(sp + 4);
    const float4 q2 = *(const float4*)(sp + 8);
    const float4 q3 = *(const float4*)(sp + 12);
    a0.x += q0.x; a0.y += q0.y; a0.z += q0.z; a0.w += q0.w;
    a1.x += q1.x; a1.y += q1.y; a1.z += q1.z; a1.w += q1.w;
    a2.x += q2.x; a2.y += q2.y; a2.z += q2.z; a2.w += q2.w;
    a3.x += q3.x; a3.y += q3.y; a3.z += q3.z; a3.w += q3.w;
  }
  float n2 = a0.x * a0.x;
  n2 = fmaf(a0.y, a0.y, n2); n2 = fmaf(a0.z, a0.z, n2); n2 = fmaf(a0.w, a0.w, n2);
  n2 = fmaf(a1.x, a1.x, n2); n2 = fmaf(a1.y, a1.y, n2); n2 = fmaf(a1.z, a1.z, n2); n2 = fmaf(a1.w, a1.w, n2);
  n2 = fmaf(a2.x, a2.x, n2); n2 = fmaf(a2.y, a2.y, n2); n2 = fmaf(a2.z, a2.z, n2); n2 = fmaf(a2.w, a2.w, n2);
  n2 = fmaf(a3.x, a3.x, n2); n2 = fmaf(a3.y, a3.y, n2); n2 = fmaf(a3.z, a3.z, n2); n2 = fmaf(a3.w, a3.w, n2);
  const float n = sqrtf(n2);
  out[t] = n * n2 / ((1.f + n2) * (n + 1e-8f));
}

extern "C" void kernel_launch(void* const* d_in, const int* in_sizes, int n_in,
                              void* d_out, int out_size, void* d_ws, size_t ws_size,
                              hipStream_t stream) {
  const float* x   = (const float*)d_in[0];
  const float* w1  = (const float*)d_in[1];
  const float* b1  = (const float*)d_in[2];
  const float* w2  = (const float*)d_in[3];
  const float* b2  = (const float*)d_in[4];
  const float* w3  = (const float*)d_in[5];
  const float* b3  = (const float*)d_in[6];
  const float* pcw = (const float*)d_in[7];
  const float* pcb = (const float*)d_in[8];
  const float* W   = (const float*)d_in[9];
  float* out = (float*)d_out;

  char* ws = (char*)d_ws;

  // Phase 1 (convs):
  u16*   x1p = (u16*)(ws + 0);           // 14,745,600 (dead after conv3)
  u16*   A2  = (u16*)(ws + 14745600);    //  4,718,592 (dead after conv2)
  u16*   A3  = (u16*)(ws + 19464192);    //    262,144 (dead after conv3)
  u16*   y   = (u16*)(ws + 19726336);    // 10,240,000 (dead after conv3)
  u16*   P   = (u16*)(ws + 29966336);    // 40,960,000 (dead after conv2_red)
  // Phase 2 (caps):
  u16*   P3  = (u16*)(ws + 43520000);    // 20,480,000 conv3 bf16 partials
  u16*   Wbs = (u16*)(ws + 0);           // 43,520,000 f16 (written after conv3)
  float* Spart = (float*)(ws + 43520000);// 20,480,000 (reuses P3 after prep_caps)
  unsigned* u2 = (unsigned*)(ws + 64000000); // 10,240,000
  float* Sp2 = (float*)(ws + 74240000);  // 409,600
  float* vs  = (float*)(ws + 74649600);  // 16,384

  hipMemsetAsync(x1p, 0, 14745600, stream);

  prep_conv1<<<1184, 256, 0, stream>>>(w2, w3, A2, A3, x, w1, b1, x1p);
  conv2_gemm<<<252, 512, 0, stream>>>(A2, x1p, P);
  conv2_red<<<5000, 256, 0, stream>>>(P, b2, y);
  conv3_gemm<<<dim3(2, 157, 2), 256, 0, stream>>>(A3, x1p, y, P3);
  prep_caps<<<12500, 256, 0, stream>>>(W, Wbs, P3, b3, pcw, pcb, u2);

  for (int pass = 0; pass < 3; pass++) {
    caps_accb2<<<1250, 256, 0, stream>>>(u2, Wbs, vs, Spart, pass == 0 ? 1 : 0);
    caps_redB<<<dim3(16, 25), 256, 0, stream>>>(Spart, Sp2);
    if (pass == 0)      caps_v2<<<1, 256, 0, stream>>>(Sp2, vs, 0);
    else if (pass == 1) caps_v2<<<1, 256, 0, stream>>>(Sp2, vs, 1);
    else                caps_out2<<<1, 256, 0, stream>>>(Sp2, out);
  }
}